// Round 1
// baseline (9764.784 us; speedup 1.0000x reference)
//
#include <hip/hip_runtime.h>
#include <hip/hip_bf16.h>
#include <cstdint>
#include <cstddef>

#define NB 32
#define NL 256
#define NH 512
#define NE 512
#define NV 32000
#define NT 64
#define NJ 2048   // 4*H
#define NK 1024   // E+H
#define NKT 16    // k-chunks in gates partial GEMM (NK/64)

// ---------------- helpers ----------------

__device__ __forceinline__ unsigned int sortable_f32(float f) {
  unsigned int s = __float_as_uint(f);
  return (s & 0x80000000u) ? ~s : (s | 0x80000000u);
}

__device__ __forceinline__ unsigned long long pack_key(float f, int v) {
  // high 32: sortable float; low 32: ~v so ties pick smallest v (numpy argmax)
  return ((unsigned long long)sortable_f32(f) << 32) |
         (unsigned long long)(unsigned int)(~v);
}

__device__ __forceinline__ unsigned long long shfl_xor_u64(unsigned long long x, int m) {
  unsigned int lo = (unsigned int)x;
  unsigned int hi = (unsigned int)(x >> 32);
  lo = __shfl_xor(lo, m, 64);
  hi = __shfl_xor(hi, m, 64);
  return ((unsigned long long)hi << 32) | lo;
}

__device__ __forceinline__ float sigmoidf_(float x) {
  return 1.0f / (1.0f + __expf(-x) * 0.0f + expf(-x)); // keep precise expf
}

// ---------------- kernels ----------------

// K0: h0 = z@Wh.T + bh ; c0 = z@Wc.T + bc ; zero argmax keys
__global__ void k_init(const float* __restrict__ z, const float* __restrict__ Wh,
                       const float* __restrict__ bh, const float* __restrict__ Wc,
                       const float* __restrict__ bc, float* __restrict__ hbuf,
                       float* __restrict__ cbuf, unsigned long long* __restrict__ keys) {
  int idx = blockIdx.x * 256 + threadIdx.x;   // 0..16383
  int b = idx >> 9, hh = idx & 511;
  const float* zr  = z + b * NL;
  const float* whr = Wh + hh * NL;
  const float* wcr = Wc + hh * NL;
  float ah = 0.f, ac = 0.f;
  for (int k = 0; k < NL; ++k) {
    float zv = zr[k];
    ah += zv * whr[k];
    ac += zv * wcr[k];
  }
  hbuf[b * NH + hh] = ah + bh[hh];   // hbuf slot 0 (input of step 0; also x0)
  cbuf[b * NH + hh] = ac + bc[hh];
  if (idx < 64) keys[idx] = 0ULL;    // keys[2][32]
}

// K0b: WT[k][j] = (k<E ? Wih[j][k] : Whh[j][k-E])   (tiled transpose, once)
__global__ void k_transposeW(const float* __restrict__ Wih, const float* __restrict__ Whh,
                             float* __restrict__ WT) {
  __shared__ float tile[32][33];
  int j0 = blockIdx.x * 32;   // 64 tiles over NJ
  int k0 = blockIdx.y * 32;   // 32 tiles over NK
  int tx = threadIdx.x & 31;  // k in tile on load, j in tile on store
  int ty = threadIdx.x >> 5;  // 8 rows at a time
  for (int r = ty; r < 32; r += 8) {
    int j = j0 + r, k = k0 + tx;
    tile[r][tx] = (k < NE) ? Wih[j * NE + k] : Whh[j * NH + (k - NE)];
  }
  __syncthreads();
  for (int r = ty; r < 32; r += 8) {
    int k = k0 + r, j = j0 + tx;
    WT[(size_t)k * NJ + j] = tile[tx][r];
  }
}

// K1: gates partial GEMM.  grid (8 j-tiles, 16 k-chunks) x 256 threads.
// thread owns 4 consecutive j, 8 b, one 64-k chunk. Writes partials[j][b][kt].
__global__ void k_gates(const float* __restrict__ WT, const float* __restrict__ emb,
                        const float* __restrict__ hbuf, const unsigned long long* __restrict__ keys,
                        float* __restrict__ partials, int step) {
  int tid  = threadIdx.x;
  int jthr = tid & 63, bthr = tid >> 6;
  int j0 = blockIdx.x * 256 + jthr * 4;
  int k0 = blockIdx.y * 64;
  int b0 = bthr * 8;
  const float* hin = hbuf + (size_t)(step & 1) * NB * NH;

  // per-b source row for xh[k]: k<E -> x (embedding[pred] or h0), k>=E -> h (recurrent)
  const float* xp[8];
  bool isx = (k0 < NE);
#pragma unroll
  for (int i = 0; i < 8; ++i) {
    int b = b0 + i;
    if (!isx) {
      xp[i] = hin + (size_t)b * NH - NE;              // xp[i][k], k in [E, E+H)
    } else if (step == 0) {
      xp[i] = hin + (size_t)b * NE;                   // x0 = h0 (E==H)
    } else {
      unsigned long long key = keys[((step - 1) & 1) * NB + b];
      unsigned int pred = ~(unsigned int)(key & 0xFFFFFFFFu);
      xp[i] = emb + (size_t)pred * NE;
    }
  }

  float acc[4][8];
#pragma unroll
  for (int jj = 0; jj < 4; ++jj)
#pragma unroll
    for (int i = 0; i < 8; ++i) acc[jj][i] = 0.f;

#pragma unroll 4
  for (int k = k0; k < k0 + 64; ++k) {
    float4 w = *(const float4*)(WT + (size_t)k * NJ + j0);
#pragma unroll
    for (int i = 0; i < 8; ++i) {
      float xv = xp[i][k];
      acc[0][i] += w.x * xv;
      acc[1][i] += w.y * xv;
      acc[2][i] += w.z * xv;
      acc[3][i] += w.w * xv;
    }
  }

  int kt = blockIdx.y;
#pragma unroll
  for (int jj = 0; jj < 4; ++jj)
#pragma unroll
    for (int i = 0; i < 8; ++i)
      partials[((size_t)(j0 + jj) * NB + (b0 + i)) * NKT + kt] = acc[jj][i];
}

// K2: reduce partials -> gates -> cell update -> h_new. Also resets keys[step&1].
__global__ void k_cell(const float* __restrict__ partials, const float* __restrict__ bih,
                       const float* __restrict__ bhh, float* __restrict__ hbuf,
                       float* __restrict__ cbuf, unsigned long long* __restrict__ keys, int step) {
  int idx = blockIdx.x * 256 + threadIdx.x;  // 0..16383
  int b = idx >> 9, hh = idx & 511;
  float g4[4];
#pragma unroll
  for (int g = 0; g < 4; ++g) {
    int j = g * NH + hh;
    const float4* p4 = (const float4*)(partials + ((size_t)j * NB + b) * NKT);
    float4 a0 = p4[0], a1 = p4[1], a2 = p4[2], a3 = p4[3];
    float s = ((a0.x + a0.y) + (a0.z + a0.w)) + ((a1.x + a1.y) + (a1.z + a1.w)) +
              ((a2.x + a2.y) + (a2.z + a2.w)) + ((a3.x + a3.y) + (a3.z + a3.w));
    g4[g] = s + bih[j] + bhh[j];
  }
  float ig = 1.0f / (1.0f + expf(-g4[0]));
  float fg = 1.0f / (1.0f + expf(-g4[1]));
  float gg = tanhf(g4[2]);
  float og = 1.0f / (1.0f + expf(-g4[3]));
  float c  = cbuf[b * NH + hh];
  float cn = fg * c + ig * gg;
  float hn = og * tanhf(cn);
  cbuf[b * NH + hh] = cn;
  hbuf[(size_t)((step + 1) & 1) * NB * NH + b * NH + hh] = hn;
  // reset the key slot k_logits is about to write (its last reader was step-1's k_gates)
  if (idx < NB) keys[(step & 1) * NB + idx] = 0ULL;
}

// K3: logits = h_new @ Wfc.T + bfc ; write out[b][t][v]; atomic argmax into keys.
// grid 500 blocks x 256 threads; block tile = 64 v x 32 b; thread = 1 v x 8 b.
__global__ void k_logits(const float* __restrict__ Wfc, const float* __restrict__ bfc,
                         const float* __restrict__ hbuf, float* __restrict__ out,
                         unsigned long long* __restrict__ keys, int step) {
  __shared__ float ldsW[64][68];   // pitch 68 floats = 272 B (16B aligned, min-BW b128 reads)
  __shared__ float ldsH[32][68];
  int tid = threadIdx.x;
  int v0 = blockIdx.x * 64;
  int tv = tid & 63, bq = tid >> 6;
  const float* hnew = hbuf + (size_t)((step + 1) & 1) * NB * NH;

  float acc[8];
#pragma unroll
  for (int i = 0; i < 8; ++i) acc[i] = 0.f;

  for (int kc = 0; kc < 8; ++kc) {
    int k0 = kc * 64;
    __syncthreads();
    // stage Wfc tile: 64 rows x 64 floats = 1024 float4; 4 per thread, coalesced
#pragma unroll
    for (int i = 0; i < 4; ++i) {
      int idx = tid + i * 256;
      int row = idx >> 4, c16 = idx & 15;
      float4 w = *(const float4*)(Wfc + (size_t)(v0 + row) * NH + k0 + c16 * 4);
      *(float4*)(&ldsW[row][c16 * 4]) = w;
    }
    // stage h tile: 32 x 64 = 512 float4; 2 per thread
#pragma unroll
    for (int i = 0; i < 2; ++i) {
      int idx = tid + i * 256;
      int row = idx >> 4, c16 = idx & 15;
      float4 h = *(const float4*)(hnew + (size_t)row * NH + k0 + c16 * 4);
      *(float4*)(&ldsH[row][c16 * 4]) = h;
    }
    __syncthreads();
#pragma unroll
    for (int k4 = 0; k4 < 16; ++k4) {
      float4 w = *(const float4*)(&ldsW[tv][k4 * 4]);
#pragma unroll
      for (int i = 0; i < 8; ++i) {
        float4 h = *(const float4*)(&ldsH[bq * 8 + i][k4 * 4]);
        acc[i] += w.x * h.x + w.y * h.y + w.z * h.z + w.w * h.w;
      }
    }
  }

  int v = v0 + tv;
  float bias = bfc[v];
#pragma unroll
  for (int i = 0; i < 8; ++i) {
    int b = bq * 8 + i;
    float logit = acc[i] + bias;
    out[((size_t)b * NT + step) * NV + v] = logit;
    unsigned long long key = pack_key(logit, v);
#pragma unroll
    for (int m = 32; m > 0; m >>= 1) {
      unsigned long long o = shfl_xor_u64(key, m);
      if (o > key) key = o;
    }
    if (tv == 0) atomicMax(&keys[(step & 1) * NB + b], key);
  }
}

// ---------------- host ----------------

extern "C" void kernel_launch(void* const* d_in, const int* in_sizes, int n_in,
                              void* d_out, int out_size, void* d_ws, size_t ws_size,
                              hipStream_t stream) {
  (void)in_sizes; (void)n_in; (void)out_size; (void)ws_size;
  const float* z   = (const float*)d_in[0];
  const float* emb = (const float*)d_in[1];
  const float* Wh  = (const float*)d_in[2];
  const float* bh  = (const float*)d_in[3];
  const float* Wc  = (const float*)d_in[4];
  const float* bc  = (const float*)d_in[5];
  const float* Wih = (const float*)d_in[6];
  const float* Whh = (const float*)d_in[7];
  const float* bih = (const float*)d_in[8];
  const float* bhh = (const float*)d_in[9];
  const float* Wfc = (const float*)d_in[10];
  const float* bfc = (const float*)d_in[11];
  float* out = (float*)d_out;

  float* ws = (float*)d_ws;
  float* WT       = ws;                          // 1024*2048            = 2,097,152 f
  float* partials = ws + 2097152;                // 2048*32*16           = 1,048,576 f
  float* hbuf     = ws + 3145728;                // 2*32*512             =    32,768 f
  float* cbuf     = ws + 3178496;                // 32*512               =    16,384 f
  unsigned long long* keys = (unsigned long long*)(ws + 3194880);  // 2*32 u64

  k_init<<<64, 256, 0, stream>>>(z, Wh, bh, Wc, bc, hbuf, cbuf, keys);
  k_transposeW<<<dim3(64, 32), 256, 0, stream>>>(Wih, Whh, WT);

  for (int t = 0; t < NT; ++t) {
    k_gates<<<dim3(8, 16), 256, 0, stream>>>(WT, emb, hbuf, keys, partials, t);
    k_cell<<<64, 256, 0, stream>>>(partials, bih, bhh, hbuf, cbuf, keys, t);
    k_logits<<<500, 256, 0, stream>>>(Wfc, bfc, hbuf, out, keys, t);
  }
}

// Round 2
// 3407.869 us; speedup vs baseline: 2.8654x; 2.8654x over previous
//
#include <hip/hip_runtime.h>
#include <hip/hip_bf16.h>
#include <cstdint>
#include <cstddef>

#define NB 32
#define NL 256
#define NH 512
#define NE 512
#define NV 32000
#define NT 64
#define NJ 2048   // 4*H
#define NK 1024   // E+H
#define NKT 16    // k-chunks in gates partial GEMM (NK/64)

typedef __attribute__((ext_vector_type(8))) short bf16x8;
typedef __attribute__((ext_vector_type(4))) float f32x4;

// ---------------- helpers ----------------

__device__ __forceinline__ unsigned int sortable_f32(float f) {
  unsigned int s = __float_as_uint(f);
  return (s & 0x80000000u) ? ~s : (s | 0x80000000u);
}

__device__ __forceinline__ unsigned long long pack_key(float f, int v) {
  // high 32: sortable float; low 32: ~v so ties pick smallest v (numpy argmax)
  return ((unsigned long long)sortable_f32(f) << 32) |
         (unsigned long long)(unsigned int)(~v);
}

__device__ __forceinline__ unsigned long long shfl_xor_u64(unsigned long long x, int m) {
  unsigned int lo = (unsigned int)x;
  unsigned int hi = (unsigned int)(x >> 32);
  lo = __shfl_xor(lo, m, 64);
  hi = __shfl_xor(hi, m, 64);
  return ((unsigned long long)hi << 32) | lo;
}

__device__ __forceinline__ uint32_t pack_hi16(uint32_t u0, uint32_t u1) {
  // result = [hi16(u0) in low half, hi16(u1) in high half]
  return __builtin_amdgcn_perm(u1, u0, 0x07060302u);
}

// exact 3-way bf16 truncation split of 8 fp32 values: e == A1 + A2 + A3 bitwise
__device__ __forceinline__ void split3(float4 wa, float4 wb,
                                       bf16x8& A1, bf16x8& A2, bf16x8& A3) {
  union U { uint32_t w[4]; bf16x8 v; };
  U u1, u2, u3;
  float e[8] = {wa.x, wa.y, wa.z, wa.w, wb.x, wb.y, wb.z, wb.w};
#pragma unroll
  for (int p = 0; p < 4; ++p) {
    float e0 = e[2 * p], e1 = e[2 * p + 1];
    uint32_t a0 = __float_as_uint(e0), a1 = __float_as_uint(e1);
    u1.w[p] = pack_hi16(a0, a1);
    float r0 = e0 - __uint_as_float(a0 & 0xffff0000u);
    float r1 = e1 - __uint_as_float(a1 & 0xffff0000u);
    uint32_t b0 = __float_as_uint(r0), b1 = __float_as_uint(r1);
    u2.w[p] = pack_hi16(b0, b1);
    float q0 = r0 - __uint_as_float(b0 & 0xffff0000u);
    float q1 = r1 - __uint_as_float(b1 & 0xffff0000u);
    u3.w[p] = pack_hi16(__float_as_uint(q0), __float_as_uint(q1));
  }
  A1 = u1.v; A2 = u2.v; A3 = u3.v;
}

// ---------------- kernels ----------------

// K0: h0 = z@Wh.T + bh ; c0 = z@Wc.T + bc ; zero argmax keys
__global__ void k_init(const float* __restrict__ z, const float* __restrict__ Wh,
                       const float* __restrict__ bh, const float* __restrict__ Wc,
                       const float* __restrict__ bc, float* __restrict__ hbuf,
                       float* __restrict__ cbuf, unsigned long long* __restrict__ keys) {
  int idx = blockIdx.x * 256 + threadIdx.x;   // 0..16383
  int b = idx >> 9, hh = idx & 511;
  const float* zr  = z + b * NL;
  const float* whr = Wh + hh * NL;
  const float* wcr = Wc + hh * NL;
  float ah = 0.f, ac = 0.f;
  for (int k = 0; k < NL; ++k) {
    float zv = zr[k];
    ah += zv * whr[k];
    ac += zv * wcr[k];
  }
  hbuf[b * NH + hh] = ah + bh[hh];   // hbuf slot 0 (input of step 0; also x0)
  cbuf[b * NH + hh] = ac + bc[hh];
  if (idx < 64) keys[idx] = 0ULL;    // keys[2][32]
}

// K0b: WT[k][j] = (k<E ? Wih[j][k] : Whh[j][k-E])   (tiled transpose, once)
__global__ void k_transposeW(const float* __restrict__ Wih, const float* __restrict__ Whh,
                             float* __restrict__ WT) {
  __shared__ float tile[32][33];
  int j0 = blockIdx.x * 32;   // 64 tiles over NJ
  int k0 = blockIdx.y * 32;   // 32 tiles over NK
  int tx = threadIdx.x & 31;
  int ty = threadIdx.x >> 5;
  for (int r = ty; r < 32; r += 8) {
    int j = j0 + r, k = k0 + tx;
    tile[r][tx] = (k < NE) ? Wih[j * NE + k] : Whh[j * NH + (k - NE)];
  }
  __syncthreads();
  for (int r = ty; r < 32; r += 8) {
    int k = k0 + r, j = j0 + tx;
    WT[(size_t)k * NJ + j] = tile[tx][r];
  }
}

// K1: gates partial GEMM.  grid (8 j-tiles, 16 k-chunks) x 256 threads.
__global__ void k_gates(const float* __restrict__ WT, const float* __restrict__ emb,
                        const float* __restrict__ hbuf, const unsigned long long* __restrict__ keys,
                        float* __restrict__ partials, int step) {
  int tid  = threadIdx.x;
  int jthr = tid & 63, bthr = tid >> 6;
  int j0 = blockIdx.x * 256 + jthr * 4;
  int k0 = blockIdx.y * 64;
  int b0 = bthr * 8;
  const float* hin = hbuf + (size_t)(step & 1) * NB * NH;

  const float* xp[8];
  bool isx = (k0 < NE);
#pragma unroll
  for (int i = 0; i < 8; ++i) {
    int b = b0 + i;
    if (!isx) {
      xp[i] = hin + (size_t)b * NH - NE;
    } else if (step == 0) {
      xp[i] = hin + (size_t)b * NE;   // x0 = h0 (E==H)
    } else {
      unsigned long long key = keys[((step - 1) & 1) * NB + b];
      unsigned int pred = ~(unsigned int)(key & 0xFFFFFFFFu);
      xp[i] = emb + (size_t)pred * NE;
    }
  }

  float acc[4][8];
#pragma unroll
  for (int jj = 0; jj < 4; ++jj)
#pragma unroll
    for (int i = 0; i < 8; ++i) acc[jj][i] = 0.f;

#pragma unroll 4
  for (int k = k0; k < k0 + 64; ++k) {
    float4 w = *(const float4*)(WT + (size_t)k * NJ + j0);
#pragma unroll
    for (int i = 0; i < 8; ++i) {
      float xv = xp[i][k];
      acc[0][i] += w.x * xv;
      acc[1][i] += w.y * xv;
      acc[2][i] += w.z * xv;
      acc[3][i] += w.w * xv;
    }
  }

  int kt = blockIdx.y;
#pragma unroll
  for (int jj = 0; jj < 4; ++jj)
#pragma unroll
    for (int i = 0; i < 8; ++i)
      partials[((size_t)(j0 + jj) * NB + (b0 + i)) * NKT + kt] = acc[jj][i];
}

// K2: reduce partials -> gates -> cell update -> h_new (fp32 + exact bf16 3-way split).
__global__ void k_cell(const float* __restrict__ partials, const float* __restrict__ bih,
                       const float* __restrict__ bhh, float* __restrict__ hbuf,
                       float* __restrict__ cbuf, unsigned short* __restrict__ hs,
                       unsigned long long* __restrict__ keys, int step) {
  int idx = blockIdx.x * 256 + threadIdx.x;  // 0..16383
  int b = idx >> 9, hh = idx & 511;
  float g4[4];
#pragma unroll
  for (int g = 0; g < 4; ++g) {
    int j = g * NH + hh;
    const float4* p4 = (const float4*)(partials + ((size_t)j * NB + b) * NKT);
    float4 a0 = p4[0], a1 = p4[1], a2 = p4[2], a3 = p4[3];
    float s = ((a0.x + a0.y) + (a0.z + a0.w)) + ((a1.x + a1.y) + (a1.z + a1.w)) +
              ((a2.x + a2.y) + (a2.z + a2.w)) + ((a3.x + a3.y) + (a3.z + a3.w));
    g4[g] = s + bih[j] + bhh[j];
  }
  float ig = 1.0f / (1.0f + expf(-g4[0]));
  float fg = 1.0f / (1.0f + expf(-g4[1]));
  float gg = tanhf(g4[2]);
  float og = 1.0f / (1.0f + expf(-g4[3]));
  float c  = cbuf[b * NH + hh];
  float cn = fg * c + ig * gg;
  float hn = og * tanhf(cn);
  cbuf[b * NH + hh] = cn;
  hbuf[(size_t)((step + 1) & 1) * NB * NH + b * NH + hh] = hn;

  // exact 3-way bf16 truncation split: hn == h1 + h2 + h3
  uint32_t u = __float_as_uint(hn);
  float r1 = hn - __uint_as_float(u & 0xffff0000u);
  uint32_t u2 = __float_as_uint(r1);
  float r2 = r1 - __uint_as_float(u2 & 0xffff0000u);
  uint32_t u3 = __float_as_uint(r2);
  hs[0 * NB * NH + b * NH + hh] = (unsigned short)(u >> 16);
  hs[1 * NB * NH + b * NH + hh] = (unsigned short)(u2 >> 16);
  hs[2 * NB * NH + b * NH + hh] = (unsigned short)(u3 >> 16);

  if (idx < NB) keys[(step & 1) * NB + idx] = 0ULL;
}

// K3: logits = h_new @ Wfc.T + bfc via split-bf16 MFMA (6 cross terms, ~fp32-exact).
// grid 500 x 256 (4 waves); wave -> 16 v rows (1 m-frag); block -> 64 v, all 32 b.
__global__ __launch_bounds__(256) void k_logits_mfma(
    const float* __restrict__ Wfc, const float* __restrict__ bfc,
    const unsigned short* __restrict__ hs, float* __restrict__ out,
    unsigned long long* __restrict__ keys, int step) {
  __shared__ union {
    unsigned short h[3][32][264];   // 3 splits x 32 b x 256 k (+8 pad), per k-half
    float t[32][68];                // out transpose tile (reused after k-loop)
  } lds;
  __shared__ unsigned long long kmax[32];

  int tid = threadIdx.x;
  int lane = tid & 63, wid = tid >> 6;
  int g = lane >> 4, r16 = lane & 15;
  int vwave = blockIdx.x * 64 + wid * 16;

  if (tid < 32) kmax[tid] = 0ULL;

  f32x4 acc0 = {0.f, 0.f, 0.f, 0.f};
  f32x4 acc1 = {0.f, 0.f, 0.f, 0.f};

  const float* wrow = Wfc + (size_t)(vwave + r16) * NH + g * 8;

  for (int half = 0; half < 2; ++half) {
    __syncthreads();
    // stage h splits for k in [half*256, half*256+256): 3072 x 16B chunks
#pragma unroll
    for (int i = 0; i < 12; ++i) {
      int idx = tid + i * 256;
      int s = idx >> 10, rem = idx & 1023;
      int row = rem >> 5, ch = rem & 31;
      float4 d = *(const float4*)(hs + (size_t)s * (NB * NH) + row * NH + half * 256 + ch * 8);
      *(float4*)(&lds.h[s][row][ch * 8]) = d;
    }
    __syncthreads();

#pragma unroll 2
    for (int kq = 0; kq < 8; ++kq) {
      int k0 = half * 256 + kq * 32;
      float4 wa = *(const float4*)(wrow + k0);
      float4 wb = *(const float4*)(wrow + k0 + 4);
      bf16x8 A1, A2, A3;
      split3(wa, wb, A1, A2, A3);

      int koff = kq * 32 + g * 8;
      bf16x8 B1n0 = *(const bf16x8*)(&lds.h[0][r16][koff]);
      bf16x8 B1n1 = *(const bf16x8*)(&lds.h[0][r16 + 16][koff]);
      bf16x8 B2n0 = *(const bf16x8*)(&lds.h[1][r16][koff]);
      bf16x8 B2n1 = *(const bf16x8*)(&lds.h[1][r16 + 16][koff]);
      bf16x8 B3n0 = *(const bf16x8*)(&lds.h[2][r16][koff]);
      bf16x8 B3n1 = *(const bf16x8*)(&lds.h[2][r16 + 16][koff]);

      acc0 = __builtin_amdgcn_mfma_f32_16x16x32_bf16(A1, B1n0, acc0, 0, 0, 0);
      acc0 = __builtin_amdgcn_mfma_f32_16x16x32_bf16(A1, B2n0, acc0, 0, 0, 0);
      acc0 = __builtin_amdgcn_mfma_f32_16x16x32_bf16(A2, B1n0, acc0, 0, 0, 0);
      acc0 = __builtin_amdgcn_mfma_f32_16x16x32_bf16(A2, B2n0, acc0, 0, 0, 0);
      acc0 = __builtin_amdgcn_mfma_f32_16x16x32_bf16(A1, B3n0, acc0, 0, 0, 0);
      acc0 = __builtin_amdgcn_mfma_f32_16x16x32_bf16(A3, B1n0, acc0, 0, 0, 0);

      acc1 = __builtin_amdgcn_mfma_f32_16x16x32_bf16(A1, B1n1, acc1, 0, 0, 0);
      acc1 = __builtin_amdgcn_mfma_f32_16x16x32_bf16(A1, B2n1, acc1, 0, 0, 0);
      acc1 = __builtin_amdgcn_mfma_f32_16x16x32_bf16(A2, B1n1, acc1, 0, 0, 0);
      acc1 = __builtin_amdgcn_mfma_f32_16x16x32_bf16(A2, B2n1, acc1, 0, 0, 0);
      acc1 = __builtin_amdgcn_mfma_f32_16x16x32_bf16(A1, B3n1, acc1, 0, 0, 0);
      acc1 = __builtin_amdgcn_mfma_f32_16x16x32_bf16(A3, B1n1, acc1, 0, 0, 0);
    }
  }

  // epilogue: bias, argmax keys, transposed coalesced store
  // C/D layout (verified): col = lane&15 (b within n-frag), row = 4*(lane>>4)+reg (v)
  float4 bv = *(const float4*)(bfc + vwave + g * 4);
  float lg0[4], lg1[4];
  unsigned long long key0 = 0ULL, key1 = 0ULL;
#pragma unroll
  for (int reg = 0; reg < 4; ++reg) {
    int v = vwave + 4 * g + reg;
    float bvr = (reg == 0) ? bv.x : (reg == 1) ? bv.y : (reg == 2) ? bv.z : bv.w;
    lg0[reg] = acc0[reg] + bvr;
    lg1[reg] = acc1[reg] + bvr;
    unsigned long long p0 = pack_key(lg0[reg], v);
    unsigned long long p1 = pack_key(lg1[reg], v);
    key0 = (p0 > key0) ? p0 : key0;
    key1 = (p1 > key1) ? p1 : key1;
  }
#pragma unroll
  for (int m = 16; m <= 32; m <<= 1) {
    unsigned long long o0 = shfl_xor_u64(key0, m);
    unsigned long long o1 = shfl_xor_u64(key1, m);
    key0 = (o0 > key0) ? o0 : key0;
    key1 = (o1 > key1) ? o1 : key1;
  }
  if (g == 0) {
    atomicMax(&kmax[r16], key0);
    atomicMax(&kmax[r16 + 16], key1);
  }
  __syncthreads();   // all k-loop LDS reads + kmax atomics done

  // write transposed tile: t[b][v_local]
#pragma unroll
  for (int reg = 0; reg < 4; ++reg) {
    int vloc = wid * 16 + 4 * g + reg;
    lds.t[r16][vloc] = lg0[reg];
    lds.t[r16 + 16][vloc] = lg1[reg];
  }
  __syncthreads();

  // coalesced store: 2048 floats, 8 per thread
  {
    int b = tid >> 3, seg = tid & 7;
    float4 p0 = *(const float4*)(&lds.t[b][seg * 8]);
    float4 p1 = *(const float4*)(&lds.t[b][seg * 8 + 4]);
    float* dst = out + ((size_t)b * NT + step) * NV + blockIdx.x * 64 + seg * 8;
    *(float4*)(dst) = p0;
    *(float4*)(dst + 4) = p1;
  }
  if (tid < 32) atomicMax(&keys[(step & 1) * NB + tid], kmax[tid]);
}

// ---------------- host ----------------

extern "C" void kernel_launch(void* const* d_in, const int* in_sizes, int n_in,
                              void* d_out, int out_size, void* d_ws, size_t ws_size,
                              hipStream_t stream) {
  (void)in_sizes; (void)n_in; (void)out_size; (void)ws_size;
  const float* z   = (const float*)d_in[0];
  const float* emb = (const float*)d_in[1];
  const float* Wh  = (const float*)d_in[2];
  const float* bh  = (const float*)d_in[3];
  const float* Wc  = (const float*)d_in[4];
  const float* bc  = (const float*)d_in[5];
  const float* Wih = (const float*)d_in[6];
  const float* Whh = (const float*)d_in[7];
  const float* bih = (const float*)d_in[8];
  const float* bhh = (const float*)d_in[9];
  const float* Wfc = (const float*)d_in[10];
  const float* bfc = (const float*)d_in[11];
  float* out = (float*)d_out;

  float* ws = (float*)d_ws;
  float* WT       = ws;                          // 1024*2048            = 2,097,152 f
  float* partials = ws + 2097152;                // 2048*32*16           = 1,048,576 f
  float* hbuf     = ws + 3145728;                // 2*32*512             =    32,768 f
  float* cbuf     = ws + 3178496;                // 32*512               =    16,384 f
  unsigned long long* keys = (unsigned long long*)(ws + 3194880);  // 64 u64 = 128 f
  unsigned short* hs = (unsigned short*)(ws + 3195008);            // 3*32*512 u16

  k_init<<<64, 256, 0, stream>>>(z, Wh, bh, Wc, bc, hbuf, cbuf, keys);
  k_transposeW<<<dim3(64, 32), 256, 0, stream>>>(Wih, Whh, WT);

  for (int t = 0; t < NT; ++t) {
    k_gates<<<dim3(8, 16), 256, 0, stream>>>(WT, emb, hbuf, keys, partials, t);
    k_cell<<<64, 256, 0, stream>>>(partials, bih, bhh, hbuf, cbuf, hs, keys, t);
    k_logits_mfma<<<500, 256, 0, stream>>>(Wfc, bfc, hs, out, keys, t);
  }
}